// Round 8
// baseline (700.973 us; speedup 1.0000x reference)
//
#include <hip/hip_runtime.h>
#include <hip/hip_cooperative_groups.h>
#include <math.h>

#define HID   2048
#define NEXP  64
#define NTOK  16384
#define SBLK  64      // sinkhorn blocks
#define TOLF  1e-4f
#define EPSF  1e-8f

// ---------------------------------------------------------------------------
// Kernel 1: logits partials + fused last-arriver K-reduction.
// Grid = 256 token-tiles x KS k-slices, 256 thr. Tile = 64 tok x 64 exp;
// per thread 4x4. ~50 live VGPRs -> fits the 64-reg budget at 8 waves/EU,
// 18KB LDS -> 8 blocks/CU (R7: this shape finally stopped spilling).
// NEW (R8): per-tile device-scope counter; the KS-th arriving block for a
// tile sums all KS partial slices in FIXED h-order (own slice from live
// registers) and writes L -- bit-deterministic regardless of arrival order,
// eliminating the reduce_halves dispatch. Producers release their P slice
// with one __threadfence() before the counter bump (once per block).
// ---------------------------------------------------------------------------
template <int KS, bool FUSE_RED>
__global__ __launch_bounds__(256) void gemm_logits(const float* __restrict__ x,
                                                   const float* __restrict__ W,
                                                   float* __restrict__ P,
                                                   float* __restrict__ L,
                                                   int* __restrict__ cnt) {
    __shared__ float xs[64 * 36];     // 64 tokens x 32 k (stride 36) = 9.2 KB
    __shared__ float wTs[32 * 68];    // 32 k x 64 experts (stride 68) = 8.7 KB
    __shared__ int   last_s;

    const int tile = blockIdx.x & 255;     // 0..255 -> 64-token tile
    const int half = blockIdx.x >> 8;      // 0..KS-1 -> k-slice
    const int tid  = (int)threadIdx.x;
    const int kb   = half * (HID / KS);
    constexpr int nch = (HID / KS) >> 5;   // chunks of 32 k (compile-time)
    const int tb   = tile * 64;

    const int f8 = tid & 7;                // staging: float4 column 0..7
    const int r0 = tid >> 3;               // staging: row 0..31 (rows r0, r0+32)
    const int tx = tid & 15;               // compute: experts tx*4..+3
    const int ty = tid >> 4;               // compute: tokens j*16+ty, ty 0..15

    float acc[4][4];
#pragma unroll
    for (int j = 0; j < 4; ++j) {
        acc[j][0] = 0.f; acc[j][1] = 0.f; acc[j][2] = 0.f; acc[j][3] = 0.f;
    }

    const float* xb0 = x + (size_t)(tb + r0) * HID + kb + f8 * 4;
    const float* xb1 = xb0 + (size_t)32 * HID;
    const float* wb0 = W + (size_t)r0 * HID + kb + f8 * 4;
    const float* wb1 = wb0 + (size_t)32 * HID;

    float4 px0, px1, pw0, pw1;
    px0 = *(const float4*)xb0;            // prefetch chunk 0
    px1 = *(const float4*)xb1;
    pw0 = *(const float4*)wb0;
    pw1 = *(const float4*)wb1;

    for (int c = 0; c < nch; ++c) {
        // staged regs -> LDS
        *(float4*)&xs[r0 * 36 + f8 * 4]        = px0;
        *(float4*)&xs[(r0 + 32) * 36 + f8 * 4] = px1;
        {
            const int ko = 4 * f8;
            wTs[(ko + 0) * 68 + r0] = pw0.x;
            wTs[(ko + 1) * 68 + r0] = pw0.y;
            wTs[(ko + 2) * 68 + r0] = pw0.z;
            wTs[(ko + 3) * 68 + r0] = pw0.w;
            wTs[(ko + 0) * 68 + r0 + 32] = pw1.x;
            wTs[(ko + 1) * 68 + r0 + 32] = pw1.y;
            wTs[(ko + 2) * 68 + r0 + 32] = pw1.z;
            wTs[(ko + 3) * 68 + r0 + 32] = pw1.w;
        }
        __syncthreads();

        // prefetch chunk c+1 (overlaps with compute below)
        if (c + 1 < nch) {
            const int ko = (c + 1) * 32;
            px0 = *(const float4*)(xb0 + ko);
            px1 = *(const float4*)(xb1 + ko);
            pw0 = *(const float4*)(wb0 + ko);
            pw1 = *(const float4*)(wb1 + ko);
        }

        // compute 32 k
#pragma unroll
        for (int kk = 0; kk < 32; kk += 4) {
            const float4 B0 = *(const float4*)&wTs[(kk + 0) * 68 + tx * 4];
            const float4 B1 = *(const float4*)&wTs[(kk + 1) * 68 + tx * 4];
            const float4 B2 = *(const float4*)&wTs[(kk + 2) * 68 + tx * 4];
            const float4 B3 = *(const float4*)&wTs[(kk + 3) * 68 + tx * 4];
#pragma unroll
            for (int j = 0; j < 4; ++j) {
                const float4 A = *(const float4*)&xs[(j * 16 + ty) * 36 + kk];
                acc[j][0] = fmaf(A.x, B0.x, acc[j][0]);
                acc[j][1] = fmaf(A.x, B0.y, acc[j][1]);
                acc[j][2] = fmaf(A.x, B0.z, acc[j][2]);
                acc[j][3] = fmaf(A.x, B0.w, acc[j][3]);
                acc[j][0] = fmaf(A.y, B1.x, acc[j][0]);
                acc[j][1] = fmaf(A.y, B1.y, acc[j][1]);
                acc[j][2] = fmaf(A.y, B1.z, acc[j][2]);
                acc[j][3] = fmaf(A.y, B1.w, acc[j][3]);
                acc[j][0] = fmaf(A.z, B2.x, acc[j][0]);
                acc[j][1] = fmaf(A.z, B2.y, acc[j][1]);
                acc[j][2] = fmaf(A.z, B2.z, acc[j][2]);
                acc[j][3] = fmaf(A.z, B2.w, acc[j][3]);
                acc[j][0] = fmaf(A.w, B3.x, acc[j][0]);
                acc[j][1] = fmaf(A.w, B3.y, acc[j][1]);
                acc[j][2] = fmaf(A.w, B3.z, acc[j][2]);
                acc[j][3] = fmaf(A.w, B3.w, acc[j][3]);
            }
        }
        __syncthreads();
    }

    // write this slice's partials
    float* Pb = P + (size_t)half * NTOK * NEXP + (size_t)tb * NEXP;
#pragma unroll
    for (int j = 0; j < 4; ++j) {
        *(float4*)(Pb + (size_t)(j * 16 + ty) * NEXP + tx * 4) =
            make_float4(acc[j][0], acc[j][1], acc[j][2], acc[j][3]);
    }

    if (FUSE_RED) {
        __threadfence();        // device-scope release of this block's P slice
        __syncthreads();        // all threads' stores fenced before the signal
        if (tid == 0) {
            const int old = __hip_atomic_fetch_add(&cnt[tile], 1,
                                                   __ATOMIC_ACQ_REL,
                                                   __HIP_MEMORY_SCOPE_AGENT);
            last_s = (old == KS - 1) ? 1 : 0;
        }
        __syncthreads();
        if (last_s) {
            // deterministic reduction: fixed h=0..KS-1 order, own slice from regs
            float* Lb = L + (size_t)tb * NEXP;
#pragma unroll
            for (int j = 0; j < 4; ++j) {
                float s0 = 0.f, s1 = 0.f, s2 = 0.f, s3 = 0.f;
                const size_t off = (size_t)(tb + j * 16 + ty) * NEXP + tx * 4;
#pragma unroll
                for (int h = 0; h < KS; ++h) {
                    if (h == half) {
                        s0 += acc[j][0]; s1 += acc[j][1];
                        s2 += acc[j][2]; s3 += acc[j][3];
                    } else {
                        const float4 v = *(const float4*)(P + (size_t)h * NTOK * NEXP + off);
                        s0 += v.x; s1 += v.y; s2 += v.z; s3 += v.w;
                    }
                }
                *(float4*)(Lb + (size_t)(j * 16 + ty) * NEXP + tx * 4) =
                    make_float4(s0, s1, s2, s3);
            }
        }
    }
}

// ---------------------------------------------------------------------------
// Kernel 2 (cooperative): sinkhorn + top-2 + softmax gather.
// Grid = 64 blocks x 1024 threads. Wave w (0..15) of block b owns tokens
// b*256 + w*16 .. +15; lane = expert. cost in registers. nh = halves to sum
// in the prologue (1 when the fused reduction ran, 2 in the small-ws path).
// Per-iter cost is ~1 grid.sync (~2us) -- the sequential-sync floor.
// ---------------------------------------------------------------------------
__global__ __launch_bounds__(1024) void sinkhorn_router(const float* __restrict__ L,
                                                        float* __restrict__ colbuf,
                                                        float* __restrict__ out,
                                                        int nh) {
    cooperative_groups::grid_group grid = cooperative_groups::this_grid();

    __shared__ float part[16][64];
    __shared__ float redq[64][17];
    __shared__ float d1s[64];
    __shared__ float err_s;

    const int b     = blockIdx.x;   // 0..63
    const int tid   = (int)threadIdx.x;
    const int w     = tid >> 6;     // wave 0..15
    const int lane  = tid & 63;     // expert index
    const int tbase = b * 256 + w * 16;

    float logit[16], cost[16], dreg[16];
#pragma unroll
    for (int j = 0; j < 16; ++j) {
        const int t = tbase + j;
        float l = L[(size_t)t * NEXP + lane];
        for (int h = 1; h < nh; ++h)
            l += L[(size_t)h * NTOK * NEXP + (size_t)t * NEXP + lane];
        logit[j] = l;
        cost[j]  = expf(l);
        dreg[j]  = 0.0f;
    }

    float d1l   = 1.0f;   // this lane's d1[e]
    float d1old = 1.0f;   // previous d1 (used by tid<64 for err)
    int   g     = 0;

    for (;;) {
        // ---- phase A: d0 per token + per-wave column partials ----
        float colacc = 0.0f;
#pragma unroll
        for (int j = 0; j < 16; ++j) {
            float s = d1l * cost[j];
#pragma unroll
            for (int m = 32; m; m >>= 1) s += __shfl_xor(s, m, 64);
            const float d0 = (1.0f / 16384.0f) / (s + EPSF);
            dreg[j] = d0;
            colacc = fmaf(d0, cost[j], colacc);
        }
        part[w][lane] = colacc;
        __syncthreads();

        float* cb = colbuf + (size_t)(g & 1) * (NEXP * SBLK);
        if (tid < 64) {
            float s = part[0][tid];
#pragma unroll
            for (int q = 1; q < 16; ++q) s += part[q][tid];
            cb[tid * SBLK + b] = s;     // reader-coalesced layout [e][b]
        }
        grid.sync();

        // ---- phase B: cross-block column reduction, all 1024 threads ----
        {
            const int e = tid >> 4;     // 0..63
            const int q = tid & 15;     // 0..15 -> blocks q*4..q*4+3
            const float4 v = *(const float4*)(cb + e * SBLK + q * 4);
            redq[e][q] = (v.x + v.y) + (v.z + v.w);
        }
        __syncthreads();

        if (tid < 64) {
            float tot = redq[tid][0];
#pragma unroll
            for (int q = 1; q < 16; ++q) tot += redq[tid][q];
            const float d1n = (1.0f / 64.0f) / (tot + EPSF);
            float diff = fabsf(d1old - d1n);
#pragma unroll
            for (int m = 32; m; m >>= 1) diff += __shfl_xor(diff, m, 64);
            d1s[tid] = d1n;
            d1old    = d1n;
            if (tid == 0) err_s = diff * (1.0f / 64.0f);
        }
        __syncthreads();
        d1l = d1s[lane];
        const float err = err_s;
        ++g;
        if (!(err > TOLF) || g >= 512) break;   // matches while(err>tol); NaN stops
    }

    // ---- final: per token top-2 of d1*cost*d0, softmax gather ----
#pragma unroll 1
    for (int j = 0; j < 16; ++j) {
        const int t = tbase + j;
        const float v = (d1l * cost[j]) * dreg[j];

        float bv = v; int bi = lane;
#pragma unroll
        for (int m = 32; m; m >>= 1) {
            const float ov = __shfl_xor(bv, m, 64);
            const int   oi = __shfl_xor(bi, m, 64);
            if (ov > bv || (ov == bv && oi < bi)) { bv = ov; bi = oi; }
        }
        const int i1 = bi;

        const float v2 = (lane == i1) ? -INFINITY : v;
        float bv2 = v2; int bi2 = lane;
#pragma unroll
        for (int m = 32; m; m >>= 1) {
            const float ov = __shfl_xor(bv2, m, 64);
            const int   oi = __shfl_xor(bi2, m, 64);
            if (ov > bv2 || (ov == bv2 && oi < bi2)) { bv2 = ov; bi2 = oi; }
        }
        const int i2 = bi2;

        float mx = logit[j];
#pragma unroll
        for (int m = 32; m; m >>= 1) mx = fmaxf(mx, __shfl_xor(mx, m, 64));
        const float e = expf(logit[j] - mx);
        float se = e;
#pragma unroll
        for (int m = 32; m; m >>= 1) se += __shfl_xor(se, m, 64);

        const float p1 = __shfl(e, i1, 64) / se;
        const float p2 = __shfl(e, i2, 64) / se;

        if (lane == 0) {
            out[(size_t)t * 2 + 0] = p1;
            out[(size_t)t * 2 + 1] = p2;
            out[(size_t)NTOK * 2 + (size_t)t * 2 + 0] = (float)i1;
            out[(size_t)NTOK * 2 + (size_t)t * 2 + 1] = (float)i2;
        }
    }
}

// ---------------------------------------------------------------------------
extern "C" void kernel_launch(void* const* d_in, const int* in_sizes, int n_in,
                              void* d_out, int out_size, void* d_ws, size_t ws_size,
                              hipStream_t stream) {
    const float* x = (const float*)d_in[0];
    const float* W = (const float*)d_in[1];
    float* out = (float*)d_out;

    const size_t PE      = (size_t)NTOK * NEXP;       // 1M floats per half
    const size_t colElts = (size_t)2 * NEXP * SBLK;   // 8192 floats

    // ws tiering (deterministic per harness; ws_size is fixed across calls)
    const size_t need8 = (8 * PE + PE + colElts) * sizeof(float) + 1024;  // ~37.8 MB
    const size_t need2 = (2 * PE + PE + colElts) * sizeof(float) + 1024;  // ~12.6 MB

    float* P = (float*)d_ws;
    if (ws_size >= need8) {
        // KS = 8: 2048 gemm blocks (8/CU), fused last-arriver reduction -> L.
        float* L      = P + 8 * PE;
        float* colbuf = L + PE;
        int*   cnt    = (int*)(colbuf + colElts);
        hipMemsetAsync(cnt, 0, 256 * sizeof(int), stream);
        gemm_logits<8, true><<<dim3(256 * 8), dim3(256), 0, stream>>>(x, W, P, L, cnt);
        int nh = 1;
        void* args[] = { (void*)&L, (void*)&colbuf, (void*)&out, (void*)&nh };
        hipLaunchCooperativeKernel((void*)sinkhorn_router, dim3(SBLK), dim3(1024),
                                   args, 0, stream);
    } else if (ws_size >= need2) {
        // KS = 2: 512 gemm blocks, fused reduction -> L.
        float* L      = P + 2 * PE;
        float* colbuf = L + PE;
        int*   cnt    = (int*)(colbuf + colElts);
        hipMemsetAsync(cnt, 0, 256 * sizeof(int), stream);
        gemm_logits<2, true><<<dim3(256 * 2), dim3(256), 0, stream>>>(x, W, P, L, cnt);
        int nh = 1;
        void* args[] = { (void*)&L, (void*)&colbuf, (void*)&out, (void*)&nh };
        hipLaunchCooperativeKernel((void*)sinkhorn_router, dim3(SBLK), dim3(1024),
                                   args, 0, stream);
    } else {
        // minimal-ws fallback (proven 8.4 MB): KS = 2, sinkhorn sums 2 halves.
        float* colbuf = P + 2 * PE;
        gemm_logits<2, false><<<dim3(256 * 2), dim3(256), 0, stream>>>(x, W, P, nullptr, nullptr);
        int nh = 2;
        void* args[] = { (void*)&P, (void*)&colbuf, (void*)&out, (void*)&nh };
        hipLaunchCooperativeKernel((void*)sinkhorn_router, dim3(SBLK), dim3(1024),
                                   args, 0, stream);
    }
}

// Round 9
// 304.620 us; speedup vs baseline: 2.3011x; 2.3011x over previous
//
#include <hip/hip_runtime.h>
#include <hip/hip_cooperative_groups.h>
#include <math.h>

#define HID   2048
#define NEXP  64
#define NTOK  16384
#define SBLK  64      // sinkhorn blocks
#define TOLF  1e-4f
#define EPSF  1e-8f

// ---------------------------------------------------------------------------
// Kernel 1: logits partials. Grid = 256 token-tiles x KS k-slices, 256 thr.
// Tile = 64 tokens x 64 experts; per thread 4 tokens x 4 experts.
// ~50 live VGPRs fits the 64-reg budget at 8 waves/EU; 18KB LDS -> 8
// blocks/CU = 32 waves/CU (R7: the only shape that never spilled).
// R8 lesson: do NOT fuse the K-reduction with per-block device-scope fences
// (2048 L2-writeback releases serialized -> 484us). The dispatch boundary
// before reduce_halves is the cheap release.
// P[half][t][e] = sum_{k in slice} x[t][k] * W[e][k]
// ---------------------------------------------------------------------------
template <int KS>
__global__ __launch_bounds__(256) void gemm_logits(const float* __restrict__ x,
                                                   const float* __restrict__ W,
                                                   float* __restrict__ P) {
    __shared__ float xs[64 * 36];     // 64 tokens x 32 k (stride 36) = 9.2 KB
    __shared__ float wTs[32 * 68];    // 32 k x 64 experts (stride 68) = 8.7 KB

    const int tile = blockIdx.x & 255;     // 0..255 -> 64-token tile
    const int half = blockIdx.x >> 8;      // 0..KS-1 -> k-slice
    const int tid  = (int)threadIdx.x;
    const int kb   = half * (HID / KS);
    constexpr int nch = (HID / KS) >> 5;   // chunks of 32 k (compile-time)
    const int tb   = tile * 64;

    const int f8 = tid & 7;                // staging: float4 column 0..7
    const int r0 = tid >> 3;               // staging: row 0..31 (rows r0, r0+32)
    const int tx = tid & 15;               // compute: experts tx*4..+3
    const int ty = tid >> 4;               // compute: tokens j*16+ty, ty 0..15

    float acc[4][4];
#pragma unroll
    for (int j = 0; j < 4; ++j) {
        acc[j][0] = 0.f; acc[j][1] = 0.f; acc[j][2] = 0.f; acc[j][3] = 0.f;
    }

    const float* xb0 = x + (size_t)(tb + r0) * HID + kb + f8 * 4;
    const float* xb1 = xb0 + (size_t)32 * HID;
    const float* wb0 = W + (size_t)r0 * HID + kb + f8 * 4;
    const float* wb1 = wb0 + (size_t)32 * HID;

    float4 px0, px1, pw0, pw1;
    px0 = *(const float4*)xb0;            // prefetch chunk 0
    px1 = *(const float4*)xb1;
    pw0 = *(const float4*)wb0;
    pw1 = *(const float4*)wb1;

    for (int c = 0; c < nch; ++c) {
        // staged regs -> LDS
        *(float4*)&xs[r0 * 36 + f8 * 4]        = px0;
        *(float4*)&xs[(r0 + 32) * 36 + f8 * 4] = px1;
        {
            const int ko = 4 * f8;
            wTs[(ko + 0) * 68 + r0] = pw0.x;
            wTs[(ko + 1) * 68 + r0] = pw0.y;
            wTs[(ko + 2) * 68 + r0] = pw0.z;
            wTs[(ko + 3) * 68 + r0] = pw0.w;
            wTs[(ko + 0) * 68 + r0 + 32] = pw1.x;
            wTs[(ko + 1) * 68 + r0 + 32] = pw1.y;
            wTs[(ko + 2) * 68 + r0 + 32] = pw1.z;
            wTs[(ko + 3) * 68 + r0 + 32] = pw1.w;
        }
        __syncthreads();

        // prefetch chunk c+1 (overlaps with compute below)
        if (c + 1 < nch) {
            const int ko = (c + 1) * 32;
            px0 = *(const float4*)(xb0 + ko);
            px1 = *(const float4*)(xb1 + ko);
            pw0 = *(const float4*)(wb0 + ko);
            pw1 = *(const float4*)(wb1 + ko);
        }

        // compute 32 k
#pragma unroll
        for (int kk = 0; kk < 32; kk += 4) {
            const float4 B0 = *(const float4*)&wTs[(kk + 0) * 68 + tx * 4];
            const float4 B1 = *(const float4*)&wTs[(kk + 1) * 68 + tx * 4];
            const float4 B2 = *(const float4*)&wTs[(kk + 2) * 68 + tx * 4];
            const float4 B3 = *(const float4*)&wTs[(kk + 3) * 68 + tx * 4];
#pragma unroll
            for (int j = 0; j < 4; ++j) {
                const float4 A = *(const float4*)&xs[(j * 16 + ty) * 36 + kk];
                acc[j][0] = fmaf(A.x, B0.x, acc[j][0]);
                acc[j][1] = fmaf(A.x, B0.y, acc[j][1]);
                acc[j][2] = fmaf(A.x, B0.z, acc[j][2]);
                acc[j][3] = fmaf(A.x, B0.w, acc[j][3]);
                acc[j][0] = fmaf(A.y, B1.x, acc[j][0]);
                acc[j][1] = fmaf(A.y, B1.y, acc[j][1]);
                acc[j][2] = fmaf(A.y, B1.z, acc[j][2]);
                acc[j][3] = fmaf(A.y, B1.w, acc[j][3]);
                acc[j][0] = fmaf(A.z, B2.x, acc[j][0]);
                acc[j][1] = fmaf(A.z, B2.y, acc[j][1]);
                acc[j][2] = fmaf(A.z, B2.z, acc[j][2]);
                acc[j][3] = fmaf(A.z, B2.w, acc[j][3]);
                acc[j][0] = fmaf(A.w, B3.x, acc[j][0]);
                acc[j][1] = fmaf(A.w, B3.y, acc[j][1]);
                acc[j][2] = fmaf(A.w, B3.z, acc[j][2]);
                acc[j][3] = fmaf(A.w, B3.w, acc[j][3]);
            }
        }
        __syncthreads();
    }

    float* Pb = P + (size_t)half * NTOK * NEXP + (size_t)tb * NEXP;
#pragma unroll
    for (int j = 0; j < 4; ++j) {
        *(float4*)(Pb + (size_t)(j * 16 + ty) * NEXP + tx * 4) =
            make_float4(acc[j][0], acc[j][1], acc[j][2], acc[j][3]);
    }
}

// ---------------------------------------------------------------------------
// Kernel 1b: collapse KS k-partials into L[t][e] with the full grid (fast),
// so the 64-block sinkhorn prologue only reads 4 MB. The dispatch boundary
// is the (cheap) device-scope release for the producers' P slices.
// ---------------------------------------------------------------------------
__global__ __launch_bounds__(256) void reduce_halves(const float* __restrict__ P,
                                                     float* __restrict__ L,
                                                     int KS) {
    const size_t i = ((size_t)blockIdx.x * 256 + threadIdx.x) * 4;
    float4 s = *(const float4*)(P + i);
    for (int h = 1; h < KS; ++h) {
        const float4 v = *(const float4*)(P + (size_t)h * NTOK * NEXP + i);
        s.x += v.x; s.y += v.y; s.z += v.z; s.w += v.w;
    }
    *(float4*)(L + i) = s;
}

// ---------------------------------------------------------------------------
// Kernel 2 (cooperative): sinkhorn + top-2 + softmax gather.
// Grid = 64 blocks x 1024 threads. Wave w (0..15) of block b owns tokens
// b*256 + w*16 .. +15; lane = expert. cost in registers. nh = halves to sum
// in the prologue (1 when reduce_halves ran, 2 in the small-ws fallback).
// Per-iter cost ~1 grid.sync (~2us) x ~24 data-dependent iterations -- the
// sequential-sync floor for any grid-wide iterative scheme.
// ---------------------------------------------------------------------------
__global__ __launch_bounds__(1024) void sinkhorn_router(const float* __restrict__ L,
                                                        float* __restrict__ colbuf,
                                                        float* __restrict__ out,
                                                        int nh) {
    cooperative_groups::grid_group grid = cooperative_groups::this_grid();

    __shared__ float part[16][64];
    __shared__ float redq[64][17];
    __shared__ float d1s[64];
    __shared__ float err_s;

    const int b     = blockIdx.x;   // 0..63
    const int tid   = (int)threadIdx.x;
    const int w     = tid >> 6;     // wave 0..15
    const int lane  = tid & 63;     // expert index
    const int tbase = b * 256 + w * 16;

    float logit[16], cost[16], dreg[16];
#pragma unroll
    for (int j = 0; j < 16; ++j) {
        const int t = tbase + j;
        float l = L[(size_t)t * NEXP + lane];
        for (int h = 1; h < nh; ++h)
            l += L[(size_t)h * NTOK * NEXP + (size_t)t * NEXP + lane];
        logit[j] = l;
        cost[j]  = expf(l);
        dreg[j]  = 0.0f;
    }

    float d1l   = 1.0f;   // this lane's d1[e]
    float d1old = 1.0f;   // previous d1 (used by tid<64 for err)
    int   g     = 0;

    for (;;) {
        // ---- phase A: d0 per token + per-wave column partials ----
        float colacc = 0.0f;
#pragma unroll
        for (int j = 0; j < 16; ++j) {
            float s = d1l * cost[j];
#pragma unroll
            for (int m = 32; m; m >>= 1) s += __shfl_xor(s, m, 64);
            const float d0 = (1.0f / 16384.0f) / (s + EPSF);
            dreg[j] = d0;
            colacc = fmaf(d0, cost[j], colacc);
        }
        part[w][lane] = colacc;
        __syncthreads();

        float* cb = colbuf + (size_t)(g & 1) * (NEXP * SBLK);
        if (tid < 64) {
            float s = part[0][tid];
#pragma unroll
            for (int q = 1; q < 16; ++q) s += part[q][tid];
            cb[tid * SBLK + b] = s;     // reader-coalesced layout [e][b]
        }
        grid.sync();

        // ---- phase B: cross-block column reduction, all 1024 threads ----
        {
            const int e = tid >> 4;     // 0..63
            const int q = tid & 15;     // 0..15 -> blocks q*4..q*4+3
            const float4 v = *(const float4*)(cb + e * SBLK + q * 4);
            redq[e][q] = (v.x + v.y) + (v.z + v.w);
        }
        __syncthreads();

        if (tid < 64) {
            float tot = redq[tid][0];
#pragma unroll
            for (int q = 1; q < 16; ++q) tot += redq[tid][q];
            const float d1n = (1.0f / 64.0f) / (tot + EPSF);
            float diff = fabsf(d1old - d1n);
#pragma unroll
            for (int m = 32; m; m >>= 1) diff += __shfl_xor(diff, m, 64);
            d1s[tid] = d1n;
            d1old    = d1n;
            if (tid == 0) err_s = diff * (1.0f / 64.0f);
        }
        __syncthreads();
        d1l = d1s[lane];
        const float err = err_s;
        ++g;
        if (!(err > TOLF) || g >= 512) break;   // matches while(err>tol); NaN stops
    }

    // ---- final: per token top-2 of d1*cost*d0, softmax gather ----
#pragma unroll 1
    for (int j = 0; j < 16; ++j) {
        const int t = tbase + j;
        const float v = (d1l * cost[j]) * dreg[j];

        float bv = v; int bi = lane;
#pragma unroll
        for (int m = 32; m; m >>= 1) {
            const float ov = __shfl_xor(bv, m, 64);
            const int   oi = __shfl_xor(bi, m, 64);
            if (ov > bv || (ov == bv && oi < bi)) { bv = ov; bi = oi; }
        }
        const int i1 = bi;

        const float v2 = (lane == i1) ? -INFINITY : v;
        float bv2 = v2; int bi2 = lane;
#pragma unroll
        for (int m = 32; m; m >>= 1) {
            const float ov = __shfl_xor(bv2, m, 64);
            const int   oi = __shfl_xor(bi2, m, 64);
            if (ov > bv2 || (ov == bv2 && oi < bi2)) { bv2 = ov; bi2 = oi; }
        }
        const int i2 = bi2;

        float mx = logit[j];
#pragma unroll
        for (int m = 32; m; m >>= 1) mx = fmaxf(mx, __shfl_xor(mx, m, 64));
        const float e = expf(logit[j] - mx);
        float se = e;
#pragma unroll
        for (int m = 32; m; m >>= 1) se += __shfl_xor(se, m, 64);

        const float p1 = __shfl(e, i1, 64) / se;
        const float p2 = __shfl(e, i2, 64) / se;

        if (lane == 0) {
            out[(size_t)t * 2 + 0] = p1;
            out[(size_t)t * 2 + 1] = p2;
            out[(size_t)NTOK * 2 + (size_t)t * 2 + 0] = (float)i1;
            out[(size_t)NTOK * 2 + (size_t)t * 2 + 1] = (float)i2;
        }
    }
}

// ---------------------------------------------------------------------------
extern "C" void kernel_launch(void* const* d_in, const int* in_sizes, int n_in,
                              void* d_out, int out_size, void* d_ws, size_t ws_size,
                              hipStream_t stream) {
    const float* x = (const float*)d_in[0];
    const float* W = (const float*)d_in[1];
    float* out = (float*)d_out;

    const size_t PE      = (size_t)NTOK * NEXP;       // 1M floats per half
    const size_t colElts = (size_t)2 * NEXP * SBLK;   // 8192 floats

    // ws tiering (deterministic per harness; ws_size is fixed across calls)
    const size_t need8 = (8 * PE + PE + colElts) * sizeof(float);   // ~37.8 MB
    const size_t need2 = (2 * PE + PE + colElts) * sizeof(float);   // ~12.6 MB

    float* P = (float*)d_ws;
    if (ws_size >= need8) {
        // KS = 8: 2048 gemm blocks (8/CU co-resident), reduce to L.
        float* L      = P + 8 * PE;
        float* colbuf = L + PE;
        gemm_logits<8><<<dim3(256 * 8), dim3(256), 0, stream>>>(x, W, P);
        reduce_halves<<<dim3(1024), dim3(256), 0, stream>>>(P, L, 8);
        int nh = 1;
        void* args[] = { (void*)&L, (void*)&colbuf, (void*)&out, (void*)&nh };
        hipLaunchCooperativeKernel((void*)sinkhorn_router, dim3(SBLK), dim3(1024),
                                   args, 0, stream);
    } else if (ws_size >= need2) {
        // KS = 2: 512 gemm blocks, reduce to L.
        float* L      = P + 2 * PE;
        float* colbuf = L + PE;
        gemm_logits<2><<<dim3(256 * 2), dim3(256), 0, stream>>>(x, W, P);
        reduce_halves<<<dim3(1024), dim3(256), 0, stream>>>(P, L, 2);
        int nh = 1;
        void* args[] = { (void*)&L, (void*)&colbuf, (void*)&out, (void*)&nh };
        hipLaunchCooperativeKernel((void*)sinkhorn_router, dim3(SBLK), dim3(1024),
                                   args, 0, stream);
    } else {
        // minimal-ws fallback (proven 8.4 MB): KS = 2, sinkhorn sums 2 halves.
        float* colbuf = P + 2 * PE;
        gemm_logits<2><<<dim3(256 * 2), dim3(256), 0, stream>>>(x, W, P);
        int nh = 2;
        void* args[] = { (void*)&P, (void*)&colbuf, (void*)&out, (void*)&nh };
        hipLaunchCooperativeKernel((void*)sinkhorn_router, dim3(SBLK), dim3(1024),
                                   args, 0, stream);
    }
}